// Round 17
// baseline (742.417 us; speedup 1.0000x reference)
//
#include <hip/hip_runtime.h>
#include <math.h>

#define N_NODES 50000
#define N_PAD 50048            // padded rows for MFMA tiles (multiple of 128)
#define N_EDGES 800000
#define D 128
#define N_GRAPHS 64
#define EPS 1e-5f
#define PCHUNK 16
#define GSTRIPES 8             // 16-row stripes per GEMM block (128 rows)
#define SCAN_NB 196            // ceil(N_NODES/256)
#define NEG_LOG2E (-1.4426950408889634f)

typedef __attribute__((ext_vector_type(8))) short bf16x8;
typedef __attribute__((ext_vector_type(4))) float f32x4;
typedef __attribute__((ext_vector_type(2))) _Float16 h16x2;

static inline size_t align256(size_t x) { return (x + 255) & ~(size_t)255; }

// ---------- bf16 helpers ----------
__device__ inline unsigned short f2bf(float x) {
    unsigned u = __builtin_bit_cast(unsigned, x);
    u += 0x7FFFu + ((u >> 16) & 1u);      // RNE
    return (unsigned short)(u >> 16);
}
__device__ inline float bf2f(unsigned short h) {
    unsigned u = (unsigned)h << 16;
    return __builtin_bit_cast(float, u);
}
__device__ inline unsigned short f2h(float x) {   // fp32 -> fp16 RNE
    _Float16 h = (_Float16)x;
    return __builtin_bit_cast(unsigned short, h);
}

// ---------- weight prep: split + transpose ----------
__global__ void prep_w(const float* __restrict__ Wk, const float* __restrict__ Wq,
                       const float* __restrict__ Wv, const float* __restrict__ Ws,
                       unsigned short* __restrict__ Whi, unsigned short* __restrict__ Wlo)
{
    const int j = blockIdx.x & 127;
    const int mat = (blockIdx.x >> 7) & 3;
    const int layer = blockIdx.x >> 9;
    const int k = threadIdx.x;
    const float* Wsrc = (mat == 0) ? Wk : (mat == 1) ? Wq : (mat == 2) ? Wv : Ws;
    const float w = Wsrc[((size_t)layer * D + k) * D + j];
    const unsigned short hi = f2bf(w);
    const unsigned short lo = f2bf(w - bf2f(hi));
    const size_t o = (((size_t)layer * 4 + mat) * D + j) * D + k;
    Whi[o] = hi;
    Wlo[o] = lo;
}

// ---------- cast: f32 [N_NODES][128] -> bf16 [N_PAD][128] (pad rows = 0) ----------
__global__ void convert_bf16(const float* __restrict__ X, unsigned short* __restrict__ Xhi)
{
    const size_t idx = (size_t)blockIdx.x * blockDim.x + threadIdx.x;  // one per 4 elems
    if (idx >= (size_t)N_PAD * (D / 4)) return;
    const size_t n = idx >> 5;
    float4 v = make_float4(0.f, 0.f, 0.f, 0.f);
    if (n < N_NODES) v = ((const float4*)X)[idx];
    ((ushort4*)Xhi)[idx] = make_ushort4(f2bf(v.x), f2bf(v.y), f2bf(v.z), f2bf(v.w));
}

// ---------- MFMA GEMM: K,Q,V,S = X @ [Wk|Wq|Wv|Ws] + b ----------
// 2-MFMA split: acc = A_bf16*(Bhi + Blo). K,Q stored pre-scaled by -log2e.
// Wave = (pair, col-tile): pair 0 computes K AND S, pair 1 computes Q AND V
// for the same 16-col tile -> Q|V<<16 packed in-thread; NO LDS, NO barriers.
__global__ void gemm_kqvs_mfma(
    const unsigned short* __restrict__ Xhi,
    const unsigned short* __restrict__ Whi, const unsigned short* __restrict__ Wlo,
    const float* __restrict__ bk, const float* __restrict__ bq,
    const float* __restrict__ bv, const float* __restrict__ bs,
    float* __restrict__ Kb, unsigned short* __restrict__ QVh, float* __restrict__ Sb)
{
    const int tid = threadIdx.x;
    const int wave = tid >> 6;                 // 0..7
    const int pair = wave & 1;                 // 0: K,S   1: Q,V
    const int ct = (wave >> 1) + 4 * blockIdx.y;   // col tile 0..7
    const int colbase = ct * 16;
    const int lane = tid & 63;
    const int l16 = lane & 15;
    const int lhi = lane >> 4;                 // 0..3

    const int mA = pair ? 1 : 0;               // Q : K   (stored pre-scaled)
    const int mB = pair ? 2 : 3;               // V : S

    // ---- B panels once: 2 mats x 4 ksteps x hi/lo = 64 VGPR ----
    const size_t wbA = ((size_t)mA * D + colbase + l16) * D;
    const size_t wbB = ((size_t)mB * D + colbase + l16) * D;
    bf16x8 bhA[4], blA[4], bhB[4], blB[4];
    #pragma unroll
    for (int c = 0; c < 4; ++c) {
        bhA[c] = *(const bf16x8*)(Whi + wbA + c * 32 + lhi * 8);
        blA[c] = *(const bf16x8*)(Wlo + wbA + c * 32 + lhi * 8);
        bhB[c] = *(const bf16x8*)(Whi + wbB + c * 32 + lhi * 8);
        blB[c] = *(const bf16x8*)(Wlo + wbB + c * 32 + lhi * 8);
    }

    const float biasA = (pair ? bq : bk)[colbase + l16];
    const float biasB = (pair ? bv : bs)[colbase + l16];
    const int lc = colbase + l16;
    const int rbase = blockIdx.x * (16 * GSTRIPES);

    // ---- stream row stripes with one-ahead A prefetch ----
    bf16x8 an[4];
    {
        const size_t arow = (size_t)(rbase + l16) * D;
        #pragma unroll
        for (int c = 0; c < 4; ++c) an[c] = *(const bf16x8*)(Xhi + arow + c * 32 + lhi * 8);
    }
    #pragma unroll
    for (int s = 0; s < GSTRIPES; ++s) {
        bf16x8 ah[4];
        #pragma unroll
        for (int c = 0; c < 4; ++c) ah[c] = an[c];
        if (s + 1 < GSTRIPES) {
            const size_t arow = (size_t)(rbase + (s + 1) * 16 + l16) * D;
            #pragma unroll
            for (int c = 0; c < 4; ++c) an[c] = *(const bf16x8*)(Xhi + arow + c * 32 + lhi * 8);
        }
        f32x4 accA = (f32x4){0.f, 0.f, 0.f, 0.f};
        f32x4 accB = (f32x4){0.f, 0.f, 0.f, 0.f};
        #pragma unroll
        for (int c = 0; c < 4; ++c) {
            accA = __builtin_amdgcn_mfma_f32_16x16x32_bf16(ah[c], bhA[c], accA, 0, 0, 0);
            accA = __builtin_amdgcn_mfma_f32_16x16x32_bf16(ah[c], blA[c], accA, 0, 0, 0);
            accB = __builtin_amdgcn_mfma_f32_16x16x32_bf16(ah[c], bhB[c], accB, 0, 0, 0);
            accB = __builtin_amdgcn_mfma_f32_16x16x32_bf16(ah[c], blB[c], accB, 0, 0, 0);
        }
        // C tile layout: col = l16, row = lhi*4 + reg (m89-verified)
        const int r0 = rbase + s * 16;
        if (pair == 0) {
            #pragma unroll
            for (int rgi = 0; rgi < 4; ++rgi) {
                const int row = r0 + lhi * 4 + rgi;
                if (row < N_NODES) {
                    Kb[(size_t)row * D + lc] = (accA[rgi] + biasA) * NEG_LOG2E;
                    Sb[(size_t)row * D + lc] = accB[rgi] + biasB;
                }
            }
        } else {
            unsigned int* qv32 = (unsigned int*)QVh;
            #pragma unroll
            for (int rgi = 0; rgi < 4; ++rgi) {
                const int row = r0 + lhi * 4 + rgi;
                if (row < N_NODES) {
                    const unsigned qh = f2h((accA[rgi] + biasA) * NEG_LOG2E);
                    const unsigned vh = f2h(accB[rgi] + biasB);
                    qv32[(size_t)row * D + lc] = qh | (vh << 16);
                }
            }
        }
    }
}

// ---------------- CSR build ----------------
__global__ void hist_dst(const int* __restrict__ dst, int* __restrict__ cnt) {
    int e = blockIdx.x * blockDim.x + threadIdx.x;
    if (e < N_EDGES) atomicAdd(&cnt[dst[e]], 1);
}

// hierarchical exclusive scan of cnt[0..N_NODES) -> row_start, cursor
__global__ void scan_block_sums(const int* __restrict__ cnt, int* __restrict__ bsum) {
    __shared__ int s[256];
    const int t = threadIdx.x;
    const int i = blockIdx.x * 256 + t;
    s[t] = (i < N_NODES) ? cnt[i] : 0;
    __syncthreads();
    #pragma unroll
    for (int off = 128; off > 0; off >>= 1) {
        if (t < off) s[t] += s[t + off];
        __syncthreads();
    }
    if (t == 0) bsum[blockIdx.x] = s[0];
}

__global__ void scan_block_offsets(const int* __restrict__ bsum, int* __restrict__ boff) {
    __shared__ int s[256];
    const int t = threadIdx.x;
    s[t] = (t < SCAN_NB) ? bsum[t] : 0;
    __syncthreads();
    for (int off = 1; off < 256; off <<= 1) {
        const int add = (t >= off) ? s[t - off] : 0;
        __syncthreads();
        s[t] += add;
        __syncthreads();
    }
    if (t < SCAN_NB) boff[t] = (t == 0) ? 0 : s[t - 1];   // exclusive
}

__global__ void scan_final(const int* __restrict__ cnt, const int* __restrict__ boff,
                           int* __restrict__ row_start, int* __restrict__ cursor) {
    __shared__ int s[256];
    const int t = threadIdx.x;
    const int i = blockIdx.x * 256 + t;
    const int v = (i < N_NODES) ? cnt[i] : 0;
    s[t] = v;
    __syncthreads();
    for (int off = 1; off < 256; off <<= 1) {
        const int add = (t >= off) ? s[t - off] : 0;
        __syncthreads();
        s[t] += add;
        __syncthreads();
    }
    if (i < N_NODES) {
        const int excl = boff[blockIdx.x] + s[t] - v;
        row_start[i] = excl;
        cursor[i] = excl;
    }
    if (i == N_NODES - 1) {
        row_start[N_NODES] = N_EDGES;
        cursor[N_NODES] = N_EDGES;
    }
}

__global__ void fill_csr(const int* __restrict__ src, const int* __restrict__ dst,
                         int* __restrict__ cursor, int* __restrict__ col) {
    int e = blockIdx.x * blockDim.x + threadIdx.x;
    if (e < N_EDGES) {
        int d = dst[e];
        int p = atomicAdd(&cursor[d], 1);
        col[p] = src[e];
    }
}

// ---------------- Edge aggregation + skip + ReLU ----------------
// One wave per node; lane covers 4 dims via one 16B gather; half-waves split
// the edge stream (lane>=32 takes the odd edge of each pair) -> one gather
// instruction per 2 edges. col[] read as wave-uniform scalars + cndmask.
// K,Q arrive pre-scaled by -log2e: gate = rcp(1 + exp2(kd + q)).
__global__ void aggregate(const float4* __restrict__ Kb4, const uint4* __restrict__ QV4,
                          const float4* __restrict__ Sb4,
                          const int* __restrict__ row_start, const int* __restrict__ col,
                          float4* __restrict__ H4)
{
    const int wave = threadIdx.x >> 6;          // 0..3
    const int node = blockIdx.x * 4 + wave;
    const unsigned lane = threadIdx.x & 63;
    const unsigned l31 = lane & 31;
    const bool hi = lane >= 32;
    const size_t nb = (size_t)node * 32 + l31;
    const float4 kd = Kb4[nb];
    float a0 = 0.f, a1 = 0.f, a2 = 0.f, a3 = 0.f;
    const int e0 = __builtin_amdgcn_readfirstlane(row_start[node]);
    const int e1 = __builtin_amdgcn_readfirstlane(row_start[node + 1]);
    int e = e0;

#define AGG_DIM(u, comp, kdc, acc)                                              \
    {                                                                           \
        const h16x2 p = __builtin_bit_cast(h16x2, (u).comp);                    \
        acc = fmaf(__builtin_amdgcn_rcpf(1.0f + exp2f(kdc + (float)p[0])),      \
                   (float)p[1], acc);                                           \
    }
#define AGG_EDGE(u) AGG_DIM(u, x, kd.x, a0) AGG_DIM(u, y, kd.y, a1) \
                    AGG_DIM(u, z, kd.z, a2) AGG_DIM(u, w, kd.w, a3)

    for (; e + 8 <= e1; e += 8) {
        const int s0 = col[e + 0], s1 = col[e + 1], s2 = col[e + 2], s3 = col[e + 3];
        const int s4 = col[e + 4], s5 = col[e + 5], s6 = col[e + 6], s7 = col[e + 7];
        const unsigned o0 = (unsigned)(hi ? s1 : s0) * 32u + l31;
        const unsigned o1 = (unsigned)(hi ? s3 : s2) * 32u + l31;
        const unsigned o2 = (unsigned)(hi ? s5 : s4) * 32u + l31;
        const unsigned o3 = (unsigned)(hi ? s7 : s6) * 32u + l31;
        const uint4 u0 = QV4[o0];
        const uint4 u1 = QV4[o1];
        const uint4 u2 = QV4[o2];
        const uint4 u3 = QV4[o3];
        AGG_EDGE(u0) AGG_EDGE(u1) AGG_EDGE(u2) AGG_EDGE(u3)
    }
    for (; e + 2 <= e1; e += 2) {
        const int s0 = col[e + 0], s1 = col[e + 1];
        const unsigned o = (unsigned)(hi ? s1 : s0) * 32u + l31;
        const uint4 u = QV4[o];
        AGG_EDGE(u)
    }
    if (e < e1 && !hi) {
        const unsigned o = (unsigned)col[e] * 32u + l31;
        const uint4 u = QV4[o];
        AGG_EDGE(u)
    }
#undef AGG_EDGE
#undef AGG_DIM

    // combine the two half-wave partial sums (lane l <-> l+32, same dims)
    a0 += __shfl_xor(a0, 32);
    a1 += __shfl_xor(a1, 32);
    a2 += __shfl_xor(a2, 32);
    a3 += __shfl_xor(a3, 32);
    if (!hi) {
        const float4 sb = Sb4[nb];
        H4[nb] = make_float4(fmaxf(a0 + sb.x, 0.0f), fmaxf(a1 + sb.y, 0.0f),
                             fmaxf(a2 + sb.z, 0.0f), fmaxf(a3 + sb.w, 0.0f));
    }
}

// ---------------- BatchNorm over nodes ----------------
// float4 reads: thread covers dims 4*(tid&31)..+3, row group tid>>5 (8 rows/sweep).
__global__ void bn_stats(const float4* __restrict__ H4, float* __restrict__ fsum,
                         float* __restrict__ fsq)
{
    __shared__ float s1[256][4];
    __shared__ float s2[256][4];
    const int tid = threadIdx.x;
    const int dgrp = tid & 31;
    const int rowg = tid >> 5;
    float sm0 = 0.f, sm1 = 0.f, sm2 = 0.f, sm3 = 0.f;
    float q0 = 0.f, q1 = 0.f, q2 = 0.f, q3 = 0.f;
    for (int n = blockIdx.x * 8 + rowg; n < N_NODES; n += gridDim.x * 8) {
        const float4 v = H4[(size_t)n * 32 + dgrp];
        sm0 += v.x; sm1 += v.y; sm2 += v.z; sm3 += v.w;
        q0 = fmaf(v.x, v.x, q0); q1 = fmaf(v.y, v.y, q1);
        q2 = fmaf(v.z, v.z, q2); q3 = fmaf(v.w, v.w, q3);
    }
    s1[tid][0] = sm0; s1[tid][1] = sm1; s1[tid][2] = sm2; s1[tid][3] = sm3;
    s2[tid][0] = q0;  s2[tid][1] = q1;  s2[tid][2] = q2;  s2[tid][3] = q3;
    __syncthreads();
    if (tid < 128) {
        #pragma unroll
        for (int c = 0; c < 4; ++c) { s1[tid][c] += s1[tid + 128][c]; s2[tid][c] += s2[tid + 128][c]; }
    }
    __syncthreads();
    if (tid < 64) {
        #pragma unroll
        for (int c = 0; c < 4; ++c) { s1[tid][c] += s1[tid + 64][c]; s2[tid][c] += s2[tid + 64][c]; }
    }
    __syncthreads();
    if (tid < 32) {
        #pragma unroll
        for (int c = 0; c < 4; ++c) {
            const float fs = s1[tid][c] + s1[tid + 32][c];
            const float fq = s2[tid][c] + s2[tid + 32][c];
            atomicAdd(&fsum[tid * 4 + c], fs);
            atomicAdd(&fsq[tid * 4 + c], fq);
        }
    }
}

// BN apply; optionally emits the next layer's bf16 input (fused convert).
// Pad rows of Xhi keep their zeros from the one-time prep convert.
__global__ void bn_apply_fused(float* __restrict__ H, const float* __restrict__ fsum,
                               const float* __restrict__ fsq, const float* __restrict__ g,
                               const float* __restrict__ b,
                               unsigned short* __restrict__ Xhi, int write_bf)
{
    const int idx = blockIdx.x * blockDim.x + threadIdx.x;
    const int total = N_NODES * D / 4;
    if (idx >= total) return;
    float4 h = ((const float4*)H)[idx];
    float hv[4] = {h.x, h.y, h.z, h.w};
    const int dbase = (idx * 4) & 127;
    float o[4];
    #pragma unroll
    for (int c = 0; c < 4; ++c) {
        const int d = dbase + c;
        const float mu = fsum[d] * (1.0f / N_NODES);
        const float var = fsq[d] * (1.0f / N_NODES) - mu * mu;
        const float sc = g[d] * rsqrtf(var + EPS);
        o[c] = (hv[c] - mu) * sc + b[d];
    }
    ((float4*)H)[idx] = make_float4(o[0], o[1], o[2], o[3]);
    if (write_bf) {
        ((ushort4*)Xhi)[idx] = make_ushort4(f2bf(o[0]), f2bf(o[1]), f2bf(o[2]), f2bf(o[3]));
    }
}

// ---------------- Pooling ----------------
__global__ void find_gstart(const int* __restrict__ batch, int* __restrict__ gstart) {
    const int g = threadIdx.x;
    if (g > N_GRAPHS) return;
    int lo = 0, hi = N_NODES;
    while (lo < hi) {
        int mid = (lo + hi) >> 1;
        if (batch[mid] < g) lo = mid + 1; else hi = mid;
    }
    gstart[g] = lo;
}

__global__ void pool_partial(const float* __restrict__ X, const int* __restrict__ gstart,
                             float* __restrict__ psum, float* __restrict__ pmax)
{
    const int g = blockIdx.x / PCHUNK;
    const int c = blockIdx.x % PCHUNK;
    const int d = threadIdx.x;
    const int lo = gstart[g], hi = gstart[g + 1];
    float sum = 0.f, mx = -INFINITY;
    for (int n = lo + c; n < hi; n += PCHUNK) {
        const float v = X[(size_t)n * D + d];
        sum += v;
        mx = fmaxf(mx, v);
    }
    psum[(size_t)blockIdx.x * D + d] = sum;
    pmax[(size_t)blockIdx.x * D + d] = mx;
}

__global__ void pool_combine(const float* __restrict__ psum, const float* __restrict__ pmax,
                             const int* __restrict__ gstart,
                             float* __restrict__ gap, float* __restrict__ gsp)
{
    const int g = blockIdx.x;
    const int d = threadIdx.x;
    float sum = 0.f, mx = -INFINITY;
    #pragma unroll
    for (int c = 0; c < PCHUNK; ++c) {
        sum += psum[(size_t)(g * PCHUNK + c) * D + d];
        mx = fmaxf(mx, pmax[(size_t)(g * PCHUNK + c) * D + d]);
    }
    const int cnt = gstart[g + 1] - gstart[g];
    gap[g * D + d] = sum / fmaxf((float)cnt, 1.0f);
    gsp[g * D + d] = (cnt > 0) ? mx : 0.0f;
}

// ---------------- BN over rows (small) ----------------
__global__ void bn_rows(const float* __restrict__ A, int rows, int cols,
                        const float* __restrict__ g, const float* __restrict__ b,
                        float* __restrict__ out, int out_cols, int out_off)
{
    const int c = blockIdx.x * blockDim.x + threadIdx.x;
    if (c >= cols) return;
    float sum = 0.f, sq = 0.f;
    for (int r = 0; r < rows; ++r) {
        const float v = A[r * cols + c];
        sum += v; sq += v * v;
    }
    const float mu = sum / rows;
    const float var = sq / rows - mu * mu;
    const float sc = g[c] * rsqrtf(var + EPS);
    const float sh = b[c] - mu * sc;
    for (int r = 0; r < rows; ++r) {
        out[r * out_cols + out_off + c] = A[r * cols + c] * sc + sh;
    }
}

// ---------------- small GEMM: out = [relu](A @ W + bias) ----------------
__global__ void gemm_small(const float* __restrict__ A, const float* __restrict__ W,
                           const float* __restrict__ bias, float* __restrict__ out,
                           int K, int C, int relu)
{
    __shared__ float as[256];
    const int r = blockIdx.x;
    for (int k = threadIdx.x; k < K; k += blockDim.x) as[k] = A[r * K + k];
    __syncthreads();
    const int j = threadIdx.x;
    if (j < C) {
        float acc = bias[j];
        for (int k = 0; k < K; ++k) acc = fmaf(as[k], W[k * C + j], acc);
        if (relu) acc = fmaxf(acc, 0.f);
        out[r * C + j] = acc;
    }
}

extern "C" void kernel_launch(void* const* d_in, const int* in_sizes, int n_in,
                              void* d_out, int out_size, void* d_ws, size_t ws_size,
                              hipStream_t stream)
{
    const float* x     = (const float*)d_in[0];
    const int*   ei    = (const int*)d_in[1];
    const int*   srcE  = ei;
    const int*   dstE  = ei + N_EDGES;
    const int*   batch = (const int*)d_in[2];
    const float* Wk = (const float*)d_in[3];  const float* bk = (const float*)d_in[4];
    const float* Wq = (const float*)d_in[5];  const float* bq = (const float*)d_in[6];
    const float* Wv = (const float*)d_in[7];  const float* bv = (const float*)d_in[8];
    const float* Ws = (const float*)d_in[9];  const float* bs = (const float*)d_in[10];
    const float* g_cl = (const float*)d_in[11]; const float* b_cl = (const float*)d_in[12];
    const float* g_gap = (const float*)d_in[13]; const float* b_gap = (const float*)d_in[14];
    const float* g_gsp = (const float*)d_in[15]; const float* b_gsp = (const float*)d_in[16];
    const float* W1 = (const float*)d_in[17]; const float* b1 = (const float*)d_in[18];
    const float* g1 = (const float*)d_in[19]; const float* bt1 = (const float*)d_in[20];
    const float* W2 = (const float*)d_in[21]; const float* b2 = (const float*)d_in[22];
    const float* g2 = (const float*)d_in[23]; const float* bt2 = (const float*)d_in[24];
    const float* Wl = (const float*)d_in[25]; const float* bl = (const float*)d_in[26];
    float* out = (float*)d_out;

    // ---- workspace carve ----
    char* ws = (char*)d_ws;
    size_t off = 0;
    const size_t bufB = (size_t)N_NODES * D * sizeof(float);   // 25.6 MB
    float* Kb = (float*)(ws + off); off = align256(off + bufB);
    unsigned short* QVh = (unsigned short*)(ws + off); off = align256(off + bufB); // half2 packed Q,V
    float* Sb = (float*)(ws + off); off = align256(off + bufB);
    float* H  = (float*)(ws + off); off = align256(off + bufB);
    unsigned short* Xhi = (unsigned short*)(ws + off); off = align256(off + (size_t)N_PAD * D * 2);
    unsigned short* Whi = (unsigned short*)(ws + off); off = align256(off + (size_t)12 * D * D * 2);
    unsigned short* Wlo = (unsigned short*)(ws + off); off = align256(off + (size_t)12 * D * D * 2);
    float* fsum = (float*)(ws + off); off = align256(off + 128 * sizeof(float));
    float* fsq  = (float*)(ws + off); off = align256(off + 128 * sizeof(float));
    int* cnt       = (int*)(ws + off); off = align256(off + (size_t)N_NODES * sizeof(int));
    int* row_start = (int*)(ws + off); off = align256(off + (size_t)(N_NODES + 1) * sizeof(int));
    int* cursor    = (int*)(ws + off); off = align256(off + (size_t)(N_NODES + 1) * sizeof(int));
    int* colI      = (int*)(ws + off); off = align256(off + (size_t)N_EDGES * sizeof(int));
    int* bsum      = (int*)(ws + off); off = align256(off + 256 * sizeof(int));
    int* boff      = (int*)(ws + off); off = align256(off + 256 * sizeof(int));
    int* gstart    = (int*)(ws + off); off = align256(off + (N_GRAPHS + 1) * sizeof(int));
    float* psum = (float*)(ws + off); off = align256(off + (size_t)N_GRAPHS * PCHUNK * D * sizeof(float));
    float* pmax = (float*)(ws + off); off = align256(off + (size_t)N_GRAPHS * PCHUNK * D * sizeof(float));
    float* gap = (float*)(ws + off); off = align256(off + (size_t)N_GRAPHS * D * sizeof(float));
    float* gsp = (float*)(ws + off); off = align256(off + (size_t)N_GRAPHS * D * sizeof(float));
    float* h0  = (float*)(ws + off); off = align256(off + (size_t)N_GRAPHS * 256 * sizeof(float));
    float* h1  = (float*)(ws + off); off = align256(off + (size_t)N_GRAPHS * 256 * sizeof(float));
    float* h2  = (float*)(ws + off); off = align256(off + (size_t)N_GRAPHS * 128 * sizeof(float));
    if (off > ws_size) return;

    // ---- one-time prep ----
    hipMemsetAsync(cnt, 0, (size_t)N_NODES * sizeof(int), stream);
    hist_dst<<<(N_EDGES + 255) / 256, 256, 0, stream>>>(dstE, cnt);
    scan_block_sums<<<SCAN_NB, 256, 0, stream>>>(cnt, bsum);
    scan_block_offsets<<<1, 256, 0, stream>>>(bsum, boff);
    scan_final<<<SCAN_NB, 256, 0, stream>>>(cnt, boff, row_start, cursor);
    fill_csr<<<(N_EDGES + 255) / 256, 256, 0, stream>>>(srcE, dstE, cursor, colI);
    find_gstart<<<1, 128, 0, stream>>>(batch, gstart);
    prep_w<<<12 * 128, 128, 0, stream>>>(Wk, Wq, Wv, Ws, Whi, Wlo);
    convert_bf16<<<(N_PAD * (D / 4) + 255) / 256, 256, 0, stream>>>(x, Xhi);

    // ---- 3 conv layers ----
    for (int i = 0; i < 3; ++i) {
        gemm_kqvs_mfma<<<dim3(N_PAD / (16 * GSTRIPES), 2), 512, 0, stream>>>(
            Xhi,
            Whi + (size_t)i * 4 * D * D, Wlo + (size_t)i * 4 * D * D,
            bk + i * D, bq + i * D, bv + i * D, bs + i * D,
            Kb, QVh, Sb);
        aggregate<<<N_NODES / 4, 256, 0, stream>>>(
            (const float4*)Kb, (const uint4*)QVh, (const float4*)Sb, row_start, colI, (float4*)H);
        hipMemsetAsync(fsum, 0, 128 * sizeof(float), stream);
        hipMemsetAsync(fsq, 0, 128 * sizeof(float), stream);
        bn_stats<<<256, 256, 0, stream>>>((const float4*)H, fsum, fsq);
        bn_apply_fused<<<(N_NODES * D / 4 + 255) / 256, 256, 0, stream>>>(
            H, fsum, fsq, g_cl + i * D, b_cl + i * D, Xhi, (i < 2) ? 1 : 0);
    }

    // ---- pooling ----
    pool_partial<<<N_GRAPHS * PCHUNK, 128, 0, stream>>>(H, gstart, psum, pmax);
    pool_combine<<<N_GRAPHS, 128, 0, stream>>>(psum, pmax, gstart, gap, gsp);
    bn_rows<<<1, 128, 0, stream>>>(gap, N_GRAPHS, 128, g_gap, b_gap, h0, 256, 0);
    bn_rows<<<1, 128, 0, stream>>>(gsp, N_GRAPHS, 128, g_gsp, b_gsp, h0, 256, 128);

    // ---- MLP head ----
    gemm_small<<<N_GRAPHS, 256, 0, stream>>>(h0, W1, b1, h1, 256, 256, 1);
    bn_rows<<<1, 256, 0, stream>>>(h1, N_GRAPHS, 256, g1, bt1, h1, 256, 0);
    gemm_small<<<N_GRAPHS, 256, 0, stream>>>(h1, W2, b2, h2, 256, 128, 1);
    bn_rows<<<1, 128, 0, stream>>>(h2, N_GRAPHS, 128, g2, bt2, h2, 128, 0);
    gemm_small<<<N_GRAPHS, 256, 0, stream>>>(h2, Wl, bl, out, 128, 5, 0);
}

// Round 18
// 729.827 us; speedup vs baseline: 1.0173x; 1.0173x over previous
//
#include <hip/hip_runtime.h>
#include <math.h>

#define N_NODES 50000
#define N_PAD 50048            // padded rows for MFMA tiles (multiple of 128)
#define N_EDGES 800000
#define D 128
#define N_GRAPHS 64
#define EPS 1e-5f
#define PCHUNK 16
#define GSTRIPES 8             // 16-row stripes per GEMM block (128 rows)
#define SCAN_NB 196            // ceil(N_NODES/256)
#define NEG_LOG2E (-1.4426950408889634f)

typedef __attribute__((ext_vector_type(8))) short bf16x8;
typedef __attribute__((ext_vector_type(4))) float f32x4;
typedef __attribute__((ext_vector_type(2))) _Float16 h16x2;

static inline size_t align256(size_t x) { return (x + 255) & ~(size_t)255; }

// ---------- bf16 helpers ----------
__device__ inline unsigned short f2bf(float x) {
    unsigned u = __builtin_bit_cast(unsigned, x);
    u += 0x7FFFu + ((u >> 16) & 1u);      // RNE
    return (unsigned short)(u >> 16);
}
__device__ inline float bf2f(unsigned short h) {
    unsigned u = (unsigned)h << 16;
    return __builtin_bit_cast(float, u);
}
__device__ inline unsigned short f2h(float x) {   // fp32 -> fp16 RNE
    _Float16 h = (_Float16)x;
    return __builtin_bit_cast(unsigned short, h);
}

// ---------- weight prep: split + transpose ----------
__global__ void prep_w(const float* __restrict__ Wk, const float* __restrict__ Wq,
                       const float* __restrict__ Wv, const float* __restrict__ Ws,
                       unsigned short* __restrict__ Whi, unsigned short* __restrict__ Wlo)
{
    const int j = blockIdx.x & 127;
    const int mat = (blockIdx.x >> 7) & 3;
    const int layer = blockIdx.x >> 9;
    const int k = threadIdx.x;
    const float* Wsrc = (mat == 0) ? Wk : (mat == 1) ? Wq : (mat == 2) ? Wv : Ws;
    const float w = Wsrc[((size_t)layer * D + k) * D + j];
    const unsigned short hi = f2bf(w);
    const unsigned short lo = f2bf(w - bf2f(hi));
    const size_t o = (((size_t)layer * 4 + mat) * D + j) * D + k;
    Whi[o] = hi;
    Wlo[o] = lo;
}

// ---------- cast: f32 [N_NODES][128] -> bf16 [N_PAD][128] (pad rows = 0) ----------
__global__ void convert_bf16(const float* __restrict__ X, unsigned short* __restrict__ Xhi)
{
    const size_t idx = (size_t)blockIdx.x * blockDim.x + threadIdx.x;  // one per 4 elems
    if (idx >= (size_t)N_PAD * (D / 4)) return;
    const size_t n = idx >> 5;
    float4 v = make_float4(0.f, 0.f, 0.f, 0.f);
    if (n < N_NODES) v = ((const float4*)X)[idx];
    ((ushort4*)Xhi)[idx] = make_ushort4(f2bf(v.x), f2bf(v.y), f2bf(v.z), f2bf(v.w));
}

// ---------- MFMA GEMM: K,Q,V,S = X @ [Wk|Wq|Wv|Ws] + b ----------
// 2-MFMA split: acc = A_bf16*(Bhi + Blo). K,Q stored pre-scaled by -log2e.
// Wave = (pair, col-tile): pair 0 computes K AND S, pair 1 computes Q AND V
// for the same 16-col tile -> Q|V<<16 packed in-thread; NO LDS, NO barriers.
__global__ void gemm_kqvs_mfma(
    const unsigned short* __restrict__ Xhi,
    const unsigned short* __restrict__ Whi, const unsigned short* __restrict__ Wlo,
    const float* __restrict__ bk, const float* __restrict__ bq,
    const float* __restrict__ bv, const float* __restrict__ bs,
    float* __restrict__ Kb, unsigned short* __restrict__ QVh, float* __restrict__ Sb)
{
    const int tid = threadIdx.x;
    const int wave = tid >> 6;                 // 0..7
    const int pair = wave & 1;                 // 0: K,S   1: Q,V
    const int ct = (wave >> 1) + 4 * blockIdx.y;   // col tile 0..7
    const int colbase = ct * 16;
    const int lane = tid & 63;
    const int l16 = lane & 15;
    const int lhi = lane >> 4;                 // 0..3

    const int mA = pair ? 1 : 0;               // Q : K   (stored pre-scaled)
    const int mB = pair ? 2 : 3;               // V : S

    // ---- B panels once: 2 mats x 4 ksteps x hi/lo = 64 VGPR ----
    const size_t wbA = ((size_t)mA * D + colbase + l16) * D;
    const size_t wbB = ((size_t)mB * D + colbase + l16) * D;
    bf16x8 bhA[4], blA[4], bhB[4], blB[4];
    #pragma unroll
    for (int c = 0; c < 4; ++c) {
        bhA[c] = *(const bf16x8*)(Whi + wbA + c * 32 + lhi * 8);
        blA[c] = *(const bf16x8*)(Wlo + wbA + c * 32 + lhi * 8);
        bhB[c] = *(const bf16x8*)(Whi + wbB + c * 32 + lhi * 8);
        blB[c] = *(const bf16x8*)(Wlo + wbB + c * 32 + lhi * 8);
    }

    const float biasA = (pair ? bq : bk)[colbase + l16];
    const float biasB = (pair ? bv : bs)[colbase + l16];
    const int lc = colbase + l16;
    const int rbase = blockIdx.x * (16 * GSTRIPES);

    // ---- stream row stripes with one-ahead A prefetch ----
    bf16x8 an[4];
    {
        const size_t arow = (size_t)(rbase + l16) * D;
        #pragma unroll
        for (int c = 0; c < 4; ++c) an[c] = *(const bf16x8*)(Xhi + arow + c * 32 + lhi * 8);
    }
    #pragma unroll
    for (int s = 0; s < GSTRIPES; ++s) {
        bf16x8 ah[4];
        #pragma unroll
        for (int c = 0; c < 4; ++c) ah[c] = an[c];
        if (s + 1 < GSTRIPES) {
            const size_t arow = (size_t)(rbase + (s + 1) * 16 + l16) * D;
            #pragma unroll
            for (int c = 0; c < 4; ++c) an[c] = *(const bf16x8*)(Xhi + arow + c * 32 + lhi * 8);
        }
        f32x4 accA = (f32x4){0.f, 0.f, 0.f, 0.f};
        f32x4 accB = (f32x4){0.f, 0.f, 0.f, 0.f};
        #pragma unroll
        for (int c = 0; c < 4; ++c) {
            accA = __builtin_amdgcn_mfma_f32_16x16x32_bf16(ah[c], bhA[c], accA, 0, 0, 0);
            accA = __builtin_amdgcn_mfma_f32_16x16x32_bf16(ah[c], blA[c], accA, 0, 0, 0);
            accB = __builtin_amdgcn_mfma_f32_16x16x32_bf16(ah[c], bhB[c], accB, 0, 0, 0);
            accB = __builtin_amdgcn_mfma_f32_16x16x32_bf16(ah[c], blB[c], accB, 0, 0, 0);
        }
        // C tile layout: col = l16, row = lhi*4 + reg (m89-verified)
        const int r0 = rbase + s * 16;
        if (pair == 0) {
            #pragma unroll
            for (int rgi = 0; rgi < 4; ++rgi) {
                const int row = r0 + lhi * 4 + rgi;
                if (row < N_NODES) {
                    Kb[(size_t)row * D + lc] = (accA[rgi] + biasA) * NEG_LOG2E;
                    Sb[(size_t)row * D + lc] = accB[rgi] + biasB;
                }
            }
        } else {
            unsigned int* qv32 = (unsigned int*)QVh;
            #pragma unroll
            for (int rgi = 0; rgi < 4; ++rgi) {
                const int row = r0 + lhi * 4 + rgi;
                if (row < N_NODES) {
                    const unsigned qh = f2h((accA[rgi] + biasA) * NEG_LOG2E);
                    const unsigned vh = f2h(accB[rgi] + biasB);
                    qv32[(size_t)row * D + lc] = qh | (vh << 16);
                }
            }
        }
    }
}

// ---------------- CSR build ----------------
__global__ void hist_dst(const int* __restrict__ dst, int* __restrict__ cnt) {
    int e = blockIdx.x * blockDim.x + threadIdx.x;
    if (e < N_EDGES) atomicAdd(&cnt[dst[e]], 1);
}

// hierarchical exclusive scan of cnt[0..N_NODES) -> row_start, cursor
__global__ void scan_block_sums(const int* __restrict__ cnt, int* __restrict__ bsum) {
    __shared__ int s[256];
    const int t = threadIdx.x;
    const int i = blockIdx.x * 256 + t;
    s[t] = (i < N_NODES) ? cnt[i] : 0;
    __syncthreads();
    #pragma unroll
    for (int off = 128; off > 0; off >>= 1) {
        if (t < off) s[t] += s[t + off];
        __syncthreads();
    }
    if (t == 0) bsum[blockIdx.x] = s[0];
}

__global__ void scan_block_offsets(const int* __restrict__ bsum, int* __restrict__ boff) {
    __shared__ int s[256];
    const int t = threadIdx.x;
    s[t] = (t < SCAN_NB) ? bsum[t] : 0;
    __syncthreads();
    for (int off = 1; off < 256; off <<= 1) {
        const int add = (t >= off) ? s[t - off] : 0;
        __syncthreads();
        s[t] += add;
        __syncthreads();
    }
    if (t < SCAN_NB) boff[t] = (t == 0) ? 0 : s[t - 1];   // exclusive
}

__global__ void scan_final(const int* __restrict__ cnt, const int* __restrict__ boff,
                           int* __restrict__ row_start, int* __restrict__ cursor) {
    __shared__ int s[256];
    const int t = threadIdx.x;
    const int i = blockIdx.x * 256 + t;
    const int v = (i < N_NODES) ? cnt[i] : 0;
    s[t] = v;
    __syncthreads();
    for (int off = 1; off < 256; off <<= 1) {
        const int add = (t >= off) ? s[t - off] : 0;
        __syncthreads();
        s[t] += add;
        __syncthreads();
    }
    if (i < N_NODES) {
        const int excl = boff[blockIdx.x] + s[t] - v;
        row_start[i] = excl;
        cursor[i] = excl;
    }
    if (i == N_NODES - 1) {
        row_start[N_NODES] = N_EDGES;
        cursor[N_NODES] = N_EDGES;
    }
}

__global__ void fill_csr(const int* __restrict__ src, const int* __restrict__ dst,
                         int* __restrict__ cursor, int* __restrict__ col) {
    int e = blockIdx.x * blockDim.x + threadIdx.x;
    if (e < N_EDGES) {
        int d = dst[e];
        int p = atomicAdd(&cursor[d], 1);
        col[p] = src[e];
    }
}

// ---------------- Edge aggregation + skip + ReLU ----------------
// One wave per node; lane handles dims {2*lane, 2*lane+1} via one 8B gather.
// K,Q arrive pre-scaled by -log2e: gate = rcp(1 + exp2(kd + q)).
// e0/e1 forced wave-uniform (readfirstlane) -> col[] reads become scalar loads.
__global__ void aggregate(const float2* __restrict__ Kb2, const uint2* __restrict__ QV2,
                          const float2* __restrict__ Sb2,
                          const int* __restrict__ row_start, const int* __restrict__ col,
                          float2* __restrict__ H2)
{
    const int wave = threadIdx.x >> 6;          // 0..3
    const int node = blockIdx.x * 4 + wave;
    const unsigned lane = threadIdx.x & 63;
    const size_t nb = (size_t)node * 64 + lane;
    const float2 kd = Kb2[nb];
    const float2 sb = Sb2[nb];
    float acc0 = 0.f, acc1 = 0.f;
    const int e0 = __builtin_amdgcn_readfirstlane(row_start[node]);
    const int e1 = __builtin_amdgcn_readfirstlane(row_start[node + 1]);
    int e = e0;
    for (; e + 8 <= e1; e += 8) {
        unsigned off0 = (unsigned)col[e + 0] * 64u + lane;
        unsigned off1 = (unsigned)col[e + 1] * 64u + lane;
        unsigned off2 = (unsigned)col[e + 2] * 64u + lane;
        unsigned off3 = (unsigned)col[e + 3] * 64u + lane;
        unsigned off4 = (unsigned)col[e + 4] * 64u + lane;
        unsigned off5 = (unsigned)col[e + 5] * 64u + lane;
        unsigned off6 = (unsigned)col[e + 6] * 64u + lane;
        unsigned off7 = (unsigned)col[e + 7] * 64u + lane;
        const uint2 u0 = QV2[off0];
        const uint2 u1 = QV2[off1];
        const uint2 u2 = QV2[off2];
        const uint2 u3 = QV2[off3];
        const uint2 u4 = QV2[off4];
        const uint2 u5 = QV2[off5];
        const uint2 u6 = QV2[off6];
        const uint2 u7 = QV2[off7];
        #pragma unroll
        for (int j = 0; j < 8; ++j) {
            const uint2 u = (j == 0) ? u0 : (j == 1) ? u1 : (j == 2) ? u2 : (j == 3) ? u3
                          : (j == 4) ? u4 : (j == 5) ? u5 : (j == 6) ? u6 : u7;
            const h16x2 p0 = __builtin_bit_cast(h16x2, u.x);
            const h16x2 p1 = __builtin_bit_cast(h16x2, u.y);
            acc0 = fmaf(__builtin_amdgcn_rcpf(1.0f + exp2f(kd.x + (float)p0[0])), (float)p0[1], acc0);
            acc1 = fmaf(__builtin_amdgcn_rcpf(1.0f + exp2f(kd.y + (float)p1[0])), (float)p1[1], acc1);
        }
    }
    for (; e + 4 <= e1; e += 4) {
        unsigned off0 = (unsigned)col[e + 0] * 64u + lane;
        unsigned off1 = (unsigned)col[e + 1] * 64u + lane;
        unsigned off2 = (unsigned)col[e + 2] * 64u + lane;
        unsigned off3 = (unsigned)col[e + 3] * 64u + lane;
        const uint2 u0 = QV2[off0];
        const uint2 u1 = QV2[off1];
        const uint2 u2 = QV2[off2];
        const uint2 u3 = QV2[off3];
        #pragma unroll
        for (int j = 0; j < 4; ++j) {
            const uint2 u = (j == 0) ? u0 : (j == 1) ? u1 : (j == 2) ? u2 : u3;
            const h16x2 p0 = __builtin_bit_cast(h16x2, u.x);
            const h16x2 p1 = __builtin_bit_cast(h16x2, u.y);
            acc0 = fmaf(__builtin_amdgcn_rcpf(1.0f + exp2f(kd.x + (float)p0[0])), (float)p0[1], acc0);
            acc1 = fmaf(__builtin_amdgcn_rcpf(1.0f + exp2f(kd.y + (float)p1[0])), (float)p1[1], acc1);
        }
    }
    for (; e < e1; ++e) {
        const unsigned off = (unsigned)col[e] * 64u + lane;
        const uint2 u = QV2[off];
        const h16x2 p0 = __builtin_bit_cast(h16x2, u.x);
        const h16x2 p1 = __builtin_bit_cast(h16x2, u.y);
        acc0 = fmaf(__builtin_amdgcn_rcpf(1.0f + exp2f(kd.x + (float)p0[0])), (float)p0[1], acc0);
        acc1 = fmaf(__builtin_amdgcn_rcpf(1.0f + exp2f(kd.y + (float)p1[0])), (float)p1[1], acc1);
    }
    H2[nb] = make_float2(fmaxf(acc0 + sb.x, 0.0f), fmaxf(acc1 + sb.y, 0.0f));
}

// ---------------- BatchNorm over nodes ----------------
__global__ void bn_stats(const float* __restrict__ H, float* __restrict__ fsum,
                         float* __restrict__ fsq)
{
    __shared__ float s1[256], s2[256];
    const int tid = threadIdx.x;
    const int d = tid & 127;
    const int rowoff = tid >> 7;
    float sum = 0.f, sq = 0.f;
    for (int n = blockIdx.x * 2 + rowoff; n < N_NODES; n += gridDim.x * 2) {
        const float v = H[(size_t)n * D + d];
        sum += v; sq += v * v;
    }
    s1[tid] = sum; s2[tid] = sq;
    __syncthreads();
    if (tid < 128) {
        atomicAdd(&fsum[d], s1[tid] + s1[tid + 128]);
        atomicAdd(&fsq[d],  s2[tid] + s2[tid + 128]);
    }
}

// BN apply; optionally emits the next layer's bf16 input (fused convert).
// Pad rows of Xhi keep their zeros from the one-time prep convert.
__global__ void bn_apply_fused(float* __restrict__ H, const float* __restrict__ fsum,
                               const float* __restrict__ fsq, const float* __restrict__ g,
                               const float* __restrict__ b,
                               unsigned short* __restrict__ Xhi, int write_bf)
{
    const int idx = blockIdx.x * blockDim.x + threadIdx.x;
    const int total = N_NODES * D / 4;
    if (idx >= total) return;
    float4 h = ((const float4*)H)[idx];
    float hv[4] = {h.x, h.y, h.z, h.w};
    const int dbase = (idx * 4) & 127;
    float o[4];
    #pragma unroll
    for (int c = 0; c < 4; ++c) {
        const int d = dbase + c;
        const float mu = fsum[d] * (1.0f / N_NODES);
        const float var = fsq[d] * (1.0f / N_NODES) - mu * mu;
        const float sc = g[d] * rsqrtf(var + EPS);
        o[c] = (hv[c] - mu) * sc + b[d];
    }
    ((float4*)H)[idx] = make_float4(o[0], o[1], o[2], o[3]);
    if (write_bf) {
        ((ushort4*)Xhi)[idx] = make_ushort4(f2bf(o[0]), f2bf(o[1]), f2bf(o[2]), f2bf(o[3]));
    }
}

// ---------------- Pooling ----------------
__global__ void find_gstart(const int* __restrict__ batch, int* __restrict__ gstart) {
    const int g = threadIdx.x;
    if (g > N_GRAPHS) return;
    int lo = 0, hi = N_NODES;
    while (lo < hi) {
        int mid = (lo + hi) >> 1;
        if (batch[mid] < g) lo = mid + 1; else hi = mid;
    }
    gstart[g] = lo;
}

__global__ void pool_partial(const float* __restrict__ X, const int* __restrict__ gstart,
                             float* __restrict__ psum, float* __restrict__ pmax)
{
    const int g = blockIdx.x / PCHUNK;
    const int c = blockIdx.x % PCHUNK;
    const int d = threadIdx.x;
    const int lo = gstart[g], hi = gstart[g + 1];
    float sum = 0.f, mx = -INFINITY;
    for (int n = lo + c; n < hi; n += PCHUNK) {
        const float v = X[(size_t)n * D + d];
        sum += v;
        mx = fmaxf(mx, v);
    }
    psum[(size_t)blockIdx.x * D + d] = sum;
    pmax[(size_t)blockIdx.x * D + d] = mx;
}

__global__ void pool_combine(const float* __restrict__ psum, const float* __restrict__ pmax,
                             const int* __restrict__ gstart,
                             float* __restrict__ gap, float* __restrict__ gsp)
{
    const int g = blockIdx.x;
    const int d = threadIdx.x;
    float sum = 0.f, mx = -INFINITY;
    #pragma unroll
    for (int c = 0; c < PCHUNK; ++c) {
        sum += psum[(size_t)(g * PCHUNK + c) * D + d];
        mx = fmaxf(mx, pmax[(size_t)(g * PCHUNK + c) * D + d]);
    }
    const int cnt = gstart[g + 1] - gstart[g];
    gap[g * D + d] = sum / fmaxf((float)cnt, 1.0f);
    gsp[g * D + d] = (cnt > 0) ? mx : 0.0f;
}

// ---------------- BN over rows (small) ----------------
__global__ void bn_rows(const float* __restrict__ A, int rows, int cols,
                        const float* __restrict__ g, const float* __restrict__ b,
                        float* __restrict__ out, int out_cols, int out_off)
{
    const int c = blockIdx.x * blockDim.x + threadIdx.x;
    if (c >= cols) return;
    float sum = 0.f, sq = 0.f;
    for (int r = 0; r < rows; ++r) {
        const float v = A[r * cols + c];
        sum += v; sq += v * v;
    }
    const float mu = sum / rows;
    const float var = sq / rows - mu * mu;
    const float sc = g[c] * rsqrtf(var + EPS);
    const float sh = b[c] - mu * sc;
    for (int r = 0; r < rows; ++r) {
        out[r * out_cols + out_off + c] = A[r * cols + c] * sc + sh;
    }
}

// ---------------- small GEMM: out = [relu](A @ W + bias) ----------------
__global__ void gemm_small(const float* __restrict__ A, const float* __restrict__ W,
                           const float* __restrict__ bias, float* __restrict__ out,
                           int K, int C, int relu)
{
    __shared__ float as[256];
    const int r = blockIdx.x;
    for (int k = threadIdx.x; k < K; k += blockDim.x) as[k] = A[r * K + k];
    __syncthreads();
    const int j = threadIdx.x;
    if (j < C) {
        float acc = bias[j];
        for (int k = 0; k < K; ++k) acc = fmaf(as[k], W[k * C + j], acc);
        if (relu) acc = fmaxf(acc, 0.f);
        out[r * C + j] = acc;
    }
}

extern "C" void kernel_launch(void* const* d_in, const int* in_sizes, int n_in,
                              void* d_out, int out_size, void* d_ws, size_t ws_size,
                              hipStream_t stream)
{
    const float* x     = (const float*)d_in[0];
    const int*   ei    = (const int*)d_in[1];
    const int*   srcE  = ei;
    const int*   dstE  = ei + N_EDGES;
    const int*   batch = (const int*)d_in[2];
    const float* Wk = (const float*)d_in[3];  const float* bk = (const float*)d_in[4];
    const float* Wq = (const float*)d_in[5];  const float* bq = (const float*)d_in[6];
    const float* Wv = (const float*)d_in[7];  const float* bv = (const float*)d_in[8];
    const float* Ws = (const float*)d_in[9];  const float* bs = (const float*)d_in[10];
    const float* g_cl = (const float*)d_in[11]; const float* b_cl = (const float*)d_in[12];
    const float* g_gap = (const float*)d_in[13]; const float* b_gap = (const float*)d_in[14];
    const float* g_gsp = (const float*)d_in[15]; const float* b_gsp = (const float*)d_in[16];
    const float* W1 = (const float*)d_in[17]; const float* b1 = (const float*)d_in[18];
    const float* g1 = (const float*)d_in[19]; const float* bt1 = (const float*)d_in[20];
    const float* W2 = (const float*)d_in[21]; const float* b2 = (const float*)d_in[22];
    const float* g2 = (const float*)d_in[23]; const float* bt2 = (const float*)d_in[24];
    const float* Wl = (const float*)d_in[25]; const float* bl = (const float*)d_in[26];
    float* out = (float*)d_out;

    // ---- workspace carve ----
    char* ws = (char*)d_ws;
    size_t off = 0;
    const size_t bufB = (size_t)N_NODES * D * sizeof(float);   // 25.6 MB
    float* Kb = (float*)(ws + off); off = align256(off + bufB);
    unsigned short* QVh = (unsigned short*)(ws + off); off = align256(off + bufB); // half2 packed Q,V
    float* Sb = (float*)(ws + off); off = align256(off + bufB);
    float* H  = (float*)(ws + off); off = align256(off + bufB);
    unsigned short* Xhi = (unsigned short*)(ws + off); off = align256(off + (size_t)N_PAD * D * 2);
    unsigned short* Whi = (unsigned short*)(ws + off); off = align256(off + (size_t)12 * D * D * 2);
    unsigned short* Wlo = (unsigned short*)(ws + off); off = align256(off + (size_t)12 * D * D * 2);
    float* fsum = (float*)(ws + off); off = align256(off + 128 * sizeof(float));
    float* fsq  = (float*)(ws + off); off = align256(off + 128 * sizeof(float));
    int* cnt       = (int*)(ws + off); off = align256(off + (size_t)N_NODES * sizeof(int));
    int* row_start = (int*)(ws + off); off = align256(off + (size_t)(N_NODES + 1) * sizeof(int));
    int* cursor    = (int*)(ws + off); off = align256(off + (size_t)(N_NODES + 1) * sizeof(int));
    int* colI      = (int*)(ws + off); off = align256(off + (size_t)N_EDGES * sizeof(int));
    int* bsum      = (int*)(ws + off); off = align256(off + 256 * sizeof(int));
    int* boff      = (int*)(ws + off); off = align256(off + 256 * sizeof(int));
    int* gstart    = (int*)(ws + off); off = align256(off + (N_GRAPHS + 1) * sizeof(int));
    float* psum = (float*)(ws + off); off = align256(off + (size_t)N_GRAPHS * PCHUNK * D * sizeof(float));
    float* pmax = (float*)(ws + off); off = align256(off + (size_t)N_GRAPHS * PCHUNK * D * sizeof(float));
    float* gap = (float*)(ws + off); off = align256(off + (size_t)N_GRAPHS * D * sizeof(float));
    float* gsp = (float*)(ws + off); off = align256(off + (size_t)N_GRAPHS * D * sizeof(float));
    float* h0  = (float*)(ws + off); off = align256(off + (size_t)N_GRAPHS * 256 * sizeof(float));
    float* h1  = (float*)(ws + off); off = align256(off + (size_t)N_GRAPHS * 256 * sizeof(float));
    float* h2  = (float*)(ws + off); off = align256(off + (size_t)N_GRAPHS * 128 * sizeof(float));
    if (off > ws_size) return;

    // ---- one-time prep ----
    hipMemsetAsync(cnt, 0, (size_t)N_NODES * sizeof(int), stream);
    hist_dst<<<(N_EDGES + 255) / 256, 256, 0, stream>>>(dstE, cnt);
    scan_block_sums<<<SCAN_NB, 256, 0, stream>>>(cnt, bsum);
    scan_block_offsets<<<1, 256, 0, stream>>>(bsum, boff);
    scan_final<<<SCAN_NB, 256, 0, stream>>>(cnt, boff, row_start, cursor);
    fill_csr<<<(N_EDGES + 255) / 256, 256, 0, stream>>>(srcE, dstE, cursor, colI);
    find_gstart<<<1, 128, 0, stream>>>(batch, gstart);
    prep_w<<<12 * 128, 128, 0, stream>>>(Wk, Wq, Wv, Ws, Whi, Wlo);
    convert_bf16<<<(N_PAD * (D / 4) + 255) / 256, 256, 0, stream>>>(x, Xhi);

    // ---- 3 conv layers ----
    for (int i = 0; i < 3; ++i) {
        gemm_kqvs_mfma<<<dim3(N_PAD / (16 * GSTRIPES), 2), 512, 0, stream>>>(
            Xhi,
            Whi + (size_t)i * 4 * D * D, Wlo + (size_t)i * 4 * D * D,
            bk + i * D, bq + i * D, bv + i * D, bs + i * D,
            Kb, QVh, Sb);
        aggregate<<<N_NODES / 4, 256, 0, stream>>>(
            (const float2*)Kb, (const uint2*)QVh, (const float2*)Sb, row_start, colI, (float2*)H);
        hipMemsetAsync(fsum, 0, 128 * sizeof(float), stream);
        hipMemsetAsync(fsq, 0, 128 * sizeof(float), stream);
        bn_stats<<<256, 256, 0, stream>>>(H, fsum, fsq);
        bn_apply_fused<<<(N_NODES * D / 4 + 255) / 256, 256, 0, stream>>>(
            H, fsum, fsq, g_cl + i * D, b_cl + i * D, Xhi, (i < 2) ? 1 : 0);
    }

    // ---- pooling ----
    pool_partial<<<N_GRAPHS * PCHUNK, 128, 0, stream>>>(H, gstart, psum, pmax);
    pool_combine<<<N_GRAPHS, 128, 0, stream>>>(psum, pmax, gstart, gap, gsp);
    bn_rows<<<1, 128, 0, stream>>>(gap, N_GRAPHS, 128, g_gap, b_gap, h0, 256, 0);
    bn_rows<<<1, 128, 0, stream>>>(gsp, N_GRAPHS, 128, g_gsp, b_gsp, h0, 256, 128);

    // ---- MLP head ----
    gemm_small<<<N_GRAPHS, 256, 0, stream>>>(h0, W1, b1, h1, 256, 256, 1);
    bn_rows<<<1, 256, 0, stream>>>(h1, N_GRAPHS, 256, g1, bt1, h1, 256, 0);
    gemm_small<<<N_GRAPHS, 256, 0, stream>>>(h1, W2, b2, h2, 256, 128, 1);
    bn_rows<<<1, 128, 0, stream>>>(h2, N_GRAPHS, 128, g2, bt2, h2, 128, 0);
    gemm_small<<<N_GRAPHS, 256, 0, stream>>>(h2, Wl, bl, out, 128, 5, 0);
}